// Round 8
// baseline (29.600 us; speedup 1.0000x reference)
//
#include <hip/hip_runtime.h>
#include <stdint.h>
#include <math.h>

#define NB 8
#define NN 128
#define NC 64
#define DEG 10
#define HP (DEG / 2)
#define NUM_STEPS 5

// DPP pair swap: lanes 2k <-> 2k+1 (quad_perm [1,0,3,2] = 0xB1). Pure VALU.
__device__ __forceinline__ float pswap(float x) {
    return __int_as_float(__builtin_amdgcn_update_dpp(
        0, __float_as_int(x), 0xB1, 0xF, 0xF, false));
}

// ---------------------------------------------------------------------------
// Single fused kernel. Block = (b,i), 256 threads.
//
// SIM phase (wave-uniform row split): wid = tid>>6; rh = wid>>1 picks the row
// half (waves 0,1 -> rows 0..4 + self; waves 2,3 -> rows 5..9); column
// jc = (tid&63) | ((wid&1)<<6). x_s row addresses are BLOCK-UNIFORM (neighbor
// ids from scalar loads) -> compiler emits s_load through the constant cache;
// FMAs use one SGPR broadcast operand. No LDS staging of x_s at all.
// Rows p>=dsi of erow are zeroed; erow has a zero 129th column -> the
// downstream T-gather needs no masking (exact zeros by construction).
//
// SINKHORN phase (lane-pair split, unchanged from R7): j = tid>>1, h = tid&1;
// rank-factored S[p][q] == T[p][q]*a[p]*b[q], T = exp(S_hat) (exp monotone +
// row-softmax normalizes => max-subtraction unnecessary; |sim| <~ 45 keeps
// products finite). Thread h owns rows h*5..h*5+4; column sums combined via
// DPP; b-updates duplicated (identical inputs -> identical values).
// argmax_q S == argmax_q T*b (a>0 const/row); q=0 always valid (deg>=1) so
// zero slots never win. Masked entries stay EXACT zeros, matching reference.
// ---------------------------------------------------------------------------
__global__ __launch_bounds__(256, 4) void fused_kernel(
    const float* __restrict__ xs, const float* __restrict__ xt,
    const int* __restrict__ dst_s, const int* __restrict__ dst_t,
    float* __restrict__ out)
{
    __shared__ float srow[DEG + 1][NN];    // 0..9 neighbor sim rows; 10 self
    __shared__ float erow[DEG][NN + 1];    // exp rows; col NN is the zero col
    __shared__ float smax[4], ssum[4];

    const int bi  = blockIdx.x;
    const int b   = bi >> 7, i = bi & 127;
    const int tid = threadIdx.x;
    const int gs  = b * NN + i;

    // ---- s-side neighbor mask + node list (block-uniform -> scalar regs) ----
    unsigned long long slo = 0ull, shi = 0ull;
    #pragma unroll
    for (int k = 0; k < DEG; ++k) {
        int d = dst_s[gs * DEG + k] & (NN - 1);
        if (d < 64) slo |= 1ull << d; else shi |= 1ull << (d - 64);
    }
    const int dsi = __popcll(slo) + __popcll(shi);
    int sn[DEG];
    {
        unsigned long long lo = slo, hi = shi;
        #pragma unroll
        for (int q = 0; q < DEG; ++q) {    // static-indexed writes only
            int t;
            if (lo)      { t = __builtin_ctzll(lo);      lo &= lo - 1ull; }
            else if (hi) { t = 64 + __builtin_ctzll(hi); hi &= hi - 1ull; }
            else t = 0;
            sn[q] = t;
        }
    }

    // ---- sim-phase mapping (wave-uniform row half) ----
    const int wid = tid >> 6;
    const int rh  = wid >> 1;              // 0: rows 0..4 + self; 1: rows 5..9
    const int jc  = (tid & 63) | ((wid & 1) << 6);

    // ---- full x_t row jc (16 float4; dead after sim phase) ----
    const float4* xtr = (const float4*)(xt + (size_t)(b * NN + jc) * NC);
    float4 xv[NC / 4];
    #pragma unroll
    for (int k = 0; k < NC / 4; ++k) xv[k] = xtr[k];

    // ---- t-side neighbor list for sinkhorn pair j = tid>>1 ----
    const int j = tid >> 1, h = tid & 1;
    const int gt = b * NN + j;
    unsigned long long tlo = 0ull, thi = 0ull;
    #pragma unroll
    for (int k = 0; k < DEG; ++k) {
        int d = dst_t[gt * DEG + k] & (NN - 1);
        if (d < 64) tlo |= 1ull << d; else thi |= 1ull << (d - 64);
    }
    const int dtj = __popcll(tlo) + __popcll(thi);
    int ntq[DEG];
    {
        unsigned long long lo = tlo, hi = thi;
        #pragma unroll
        for (int q = 0; q < DEG; ++q) {    // static-indexed writes only
            int t;
            if (lo)      { t = __builtin_ctzll(lo);      lo &= lo - 1ull; }
            else if (hi) { t = 64 + __builtin_ctzll(hi); hi &= hi - 1ull; }
            else t = 0;
            ntq[q] = (q < dtj) ? t : NN;   // invalid -> zero column
        }
    }

    if (tid < DEG) erow[tid][NN] = 0.0f;   // zero column

    // ---- sim rows: x_s chunks via uniform (scalar) loads, FMA vs xv ----
#define SIMROW(R)                                                              \
    {                                                                          \
        if ((R) < dsi) {                                                       \
            const float4* xsr =                                                \
                (const float4*)(xs + (size_t)(b * NN + sn[(R)]) * NC);         \
            float acc = 0.f;                                                   \
            _Pragma("unroll")                                                  \
            for (int k = 0; k < NC / 4; ++k) {                                 \
                float4 a4 = xsr[k];                                            \
                acc += a4.x * xv[k].x + a4.y * xv[k].y +                       \
                       a4.z * xv[k].z + a4.w * xv[k].w;                        \
            }                                                                  \
            srow[(R)][jc] = acc;                                               \
            erow[(R)][jc] = __expf(acc);                                       \
        } else {                                                               \
            erow[(R)][jc] = 0.0f;                                              \
        }                                                                      \
    }

    if (rh == 0) {                         // wave-uniform branch
        SIMROW(0) SIMROW(1) SIMROW(2) SIMROW(3) SIMROW(4)
        {   // self row (always)
            const float4* xsr = (const float4*)(xs + (size_t)gs * NC);
            float acc = 0.f;
            #pragma unroll
            for (int k = 0; k < NC / 4; ++k) {
                float4 a4 = xsr[k];
                acc += a4.x * xv[k].x + a4.y * xv[k].y +
                       a4.z * xv[k].z + a4.w * xv[k].w;
            }
            srow[DEG][jc] = acc;
        }
    } else {
        SIMROW(5) SIMROW(6) SIMROW(7) SIMROW(8) SIMROW(9)
    }
#undef SIMROW
    __syncthreads();

    // ---- gather own half of T (unmasked: zeros by construction) ----
    float T[HP][DEG];
    float a[HP], bvv[DEG];
    #pragma unroll
    for (int q = 0; q < DEG; ++q) bvv[q] = (q < dtj) ? 1.0f : 0.0f;

    #pragma unroll
    for (int pp = 0; pp < HP; ++pp) {
        int p = h * HP + pp;
        float sum = 0.f;
        #pragma unroll
        for (int q = 0; q < DEG; ++q) {
            float e = erow[p][ntq[q]];
            T[pp][q] = e;
            sum += e;
        }
        a[pp] = (p < dsi) ? __builtin_amdgcn_rcpf(sum) * 10.0f : 0.0f;
    }

    // ---- 5 Sinkhorn iterations on the scale vectors only ----
    #pragma unroll 1
    for (int it = 0; it < NUM_STEPS; ++it) {
        float part[DEG];
        #pragma unroll
        for (int q = 0; q < DEG; ++q) {
            float cc = T[0][q] * a[0];
            #pragma unroll
            for (int pp = 1; pp < HP; ++pp) cc = fmaf(T[pp][q], a[pp], cc);
            part[q] = cc;
        }
        #pragma unroll
        for (int q = 0; q < DEG; ++q) {
            float cc = part[q] + pswap(part[q]);   // identical on both lanes
            float bq = bvv[q];
            bvv[q] = (q < dtj) ? bq * __builtin_amdgcn_rcpf(fmaf(bq, cc, 1e-8f)) : 0.0f;
        }
        #pragma unroll
        for (int pp = 0; pp < HP; ++pp) {
            float r = T[pp][0] * bvv[0];
            #pragma unroll
            for (int q = 1; q < DEG; ++q) r = fmaf(T[pp][q], bvv[q], r);
            float ap = a[pp];
            int p = h * HP + pp;
            a[pp] = (p < dsi) ? ap * __builtin_amdgcn_rcpf(fmaf(ap, r, 1e-8f)) : 0.0f;
        }
    }

    // ---- argmax per own row over T*b (first max), cost gather from LDS ----
    float cpart = 0.f;
    #pragma unroll
    for (int pp = 0; pp < HP; ++pp) {
        int p = h * HP + pp;
        if (p < dsi) {
            float best = T[pp][0] * bvv[0];   // q=0 always valid (deg>=1)
            int   bc   = ntq[0];
            #pragma unroll
            for (int q = 1; q < DEG; ++q) {
                float vq = T[pp][q] * bvv[q];
                if (vq > best) { best = vq; bc = ntq[q]; }
            }
            cpart += srow[p][bc];
        }
    }
    float cost = cpart + pswap(cpart);           // identical on both lanes

    float M = (float)((dsi > dtj) ? dsi : dtj);
    float simv = srow[DEG][j];
    float v = fmaf(cost, __builtin_amdgcn_rcpf(1.0f + M), simv);

    // ---- block softmax over j: each pair's v appears twice -> sum * 0.5 ----
    float wm = v;
    #pragma unroll
    for (int off = 32; off; off >>= 1) wm = fmaxf(wm, __shfl_xor(wm, off));
    int wsl = tid >> 6;
    if ((tid & 63) == 0) smax[wsl] = wm;
    __syncthreads();
    float bm = fmaxf(fmaxf(smax[0], smax[1]), fmaxf(smax[2], smax[3]));
    float e = __expf(v - bm);
    float wsum = e;
    #pragma unroll
    for (int off = 32; off; off >>= 1) wsum += __shfl_xor(wsum, off);
    if ((tid & 63) == 0) ssum[wsl] = wsum;
    __syncthreads();
    float bs = (ssum[0] + ssum[1] + ssum[2] + ssum[3]) * 0.5f;

    if (h == 0) out[(size_t)gs * NN + j] = e * __builtin_amdgcn_rcpf(bs);
}

// ---------------------------------------------------------------------------
extern "C" void kernel_launch(void* const* d_in, const int* in_sizes, int n_in,
                              void* d_out, int out_size, void* d_ws, size_t ws_size,
                              hipStream_t stream) {
    (void)in_sizes; (void)n_in; (void)out_size; (void)d_ws; (void)ws_size;
    const float* x_s  = (const float*)d_in[0];
    const int*   ei_s = (const int*)  d_in[1];
    const float* x_t  = (const float*)d_in[3];
    const int*   ei_t = (const int*)  d_in[4];
    float* out = (float*)d_out;

    const int* dst_s = ei_s + NB * NN * DEG;   // second row of edge_index
    const int* dst_t = ei_t + NB * NN * DEG;

    hipLaunchKernelGGL(fused_kernel, dim3(NB * NN), dim3(256), 0, stream,
                       x_s, x_t, dst_s, dst_t, out);
}

// Round 9
// 24.443 us; speedup vs baseline: 1.2110x; 1.2110x over previous
//
#include <hip/hip_runtime.h>
#include <stdint.h>
#include <math.h>

#define NB 8
#define NN 128
#define NC 64
#define DEG 10
#define HP (DEG / 2)
#define NUM_STEPS 5

// DPP pair swap: lanes 2k <-> 2k+1 (quad_perm [1,0,3,2] = 0xB1). Pure VALU —
// no LDS pipe, no lgkmcnt stall. Callers are in convergent code.
__device__ __forceinline__ float pswap(float x) {
    return __int_as_float(__builtin_amdgcn_update_dpp(
        0, __float_as_int(x), 0xB1, 0xF, 0xF, false));
}

// ---------------------------------------------------------------------------
// Single fused kernel (R7 structure, proven 24.7 us). Block = (b,i), 256
// threads; pair mapping j = tid>>1, h = tid&1 for BOTH sim and Sinkhorn.
//
// sim: thread (j,h) holds half of x_t[j] (8 float4), 32-FMA partial dots vs
// <=11 x_s rows staged in LDS, combined with one DPP swap; h==0 writes
// srow/erow. Rows p>=dsi of erow are ZEROED and erow has a zero 129th
// column -> the T-gather needs no masking (exact zeros by construction).
//
// sinkhorn: rank-factored S[p][q] == T[p][q]*a[p]*b[q], T = exp(S_hat)
// (exp monotone + row-softmax normalizes => max-subtraction unnecessary;
// |sim| <~ 45 keeps products finite). Thread h owns rows h*5..h*5+4; column
// sums split p-wise, combined via DPP; b-updates duplicated (identical
// inputs -> identical values); row phase local.
// R8 changes vs the 24.7 kernel (latency cuts only):
//  - NO per-iter predication on b/a updates: masked lanes self-preserve
//    exactly (bq==0 -> 0*rcp(1e-8)=0; invalid row: r==0 -> 0*rcp(1e-8)=0).
//  - serial fmaf chains split into two half-chains + add (depth ~halved).
// argmax_q S == argmax_q T*b (a>0 const/row); q=0 always valid (deg>=1) and
// valid entries are strictly positive -> masked (zero) slots never win.
// ---------------------------------------------------------------------------
__global__ __launch_bounds__(256, 4) void fused_kernel(
    const float* __restrict__ xs, const float* __restrict__ xt,
    const int* __restrict__ dst_s, const int* __restrict__ dst_t,
    float* __restrict__ out)
{
    __shared__ float  srow[DEG + 1][NN];    // 0..9 neighbor sim rows; 10 self
    __shared__ float  erow[DEG][NN + 1];    // exp rows; col NN is the zero col
    __shared__ float4 xsl[DEG + 1][NC / 4];
    __shared__ float  smax[4], ssum[4];

    const int bi  = blockIdx.x;
    const int b   = bi >> 7, i = bi & 127;
    const int tid = threadIdx.x;
    const int j   = tid >> 1;               // pair id / sim column
    const int h   = tid & 1;                // channel half / row half
    const int gs  = b * NN + i;
    const int gt  = b * NN + j;

    // ---- s-side neighbor mask (block-uniform) ----
    unsigned long long slo = 0ull, shi = 0ull;
    #pragma unroll
    for (int k = 0; k < DEG; ++k) {
        int d = dst_s[gs * DEG + k] & (NN - 1);
        if (d < 64) slo |= 1ull << d; else shi |= 1ull << (d - 64);
    }
    const int dsi = __popcll(slo) + __popcll(shi);

    // ---- own half of x_t row j (8 float4 = 32 VGPR), issued early ----
    const float4* xtr = (const float4*)(xt + (size_t)gt * NC) + h * (NC / 8);
    float4 xv[NC / 8];
    #pragma unroll
    for (int k = 0; k < NC / 8; ++k) xv[k] = xtr[k];

    // ---- zero column of erow ----
    if (tid < DEG) erow[tid][NN] = 0.0f;

    // ---- stage x_s rows into LDS: threads 0..175, row = tid>>4, k = tid&15 ----
    if (tid < (DEG + 1) * 16) {
        int r = tid >> 4, k = tid & 15;
        int node = i;                        // r==10 -> self row
        if (r < DEG) {
            unsigned long long lo = slo, hi = shi; int sel = 0;
            #pragma unroll
            for (int q = 0; q < DEG; ++q) {  // static walk, scalar select
                int t;
                if (lo)      { t = __builtin_ctzll(lo);      lo &= lo - 1ull; }
                else if (hi) { t = 64 + __builtin_ctzll(hi); hi &= hi - 1ull; }
                else t = 0;
                if (q == r) sel = t;
            }
            node = sel;
        }
        if (r == DEG || r < dsi)
            xsl[r][k] = ((const float4*)(xs + (size_t)(b * NN + node) * NC))[k];
    }

    // ---- t-side neighbor list for pair j (overlaps before sync) ----
    unsigned long long tlo = 0ull, thi = 0ull;
    #pragma unroll
    for (int k = 0; k < DEG; ++k) {
        int d = dst_t[gt * DEG + k] & (NN - 1);
        if (d < 64) tlo |= 1ull << d; else thi |= 1ull << (d - 64);
    }
    const int dtj = __popcll(tlo) + __popcll(thi);
    int ntq[DEG];
    {
        unsigned long long lo = tlo, hi = thi;
        #pragma unroll
        for (int q = 0; q < DEG; ++q) {      // static-indexed writes
            int t;
            if (lo)      { t = __builtin_ctzll(lo);      lo &= lo - 1ull; }
            else if (hi) { t = 64 + __builtin_ctzll(hi); hi &= hi - 1ull; }
            else t = 0;
            ntq[q] = (q < dtj) ? t : NN;     // invalid -> zero column
        }
    }
    __syncthreads();

    // ---- sim dots; rows p>=dsi: zero-fill erow so gather needs no mask ----
    #pragma unroll
    for (int r = 0; r <= DEG; ++r) {
        if (r == DEG || r < dsi) {           // wave-uniform
            float acc = 0.f;
            #pragma unroll
            for (int k = 0; k < NC / 8; ++k) {
                float4 a4 = xsl[r][h * (NC / 8) + k];
                acc += a4.x * xv[k].x + a4.y * xv[k].y + a4.z * xv[k].z + a4.w * xv[k].w;
            }
            float full = acc + pswap(acc);   // identical on both lanes
            if (h == 0) {
                srow[r][j] = full;
                if (r < DEG) erow[r][j] = __expf(full);
            }
        } else {
            if (h == 0) erow[r][j] = 0.0f;
        }
    }
    __syncthreads();

    // ---- gather own half of T (unmasked: zeros by construction) ----
    float T[HP][DEG];
    float a[HP], bvv[DEG];
    #pragma unroll
    for (int q = 0; q < DEG; ++q) bvv[q] = (q < dtj) ? 1.0f : 0.0f;

    #pragma unroll
    for (int pp = 0; pp < HP; ++pp) {
        int p = h * HP + pp;
        float s1 = 0.f, s2 = 0.f;            // split sum: depth ~5 not 10
        #pragma unroll
        for (int q = 0; q < HP; ++q) {
            float e = erow[p][ntq[q]];
            T[pp][q] = e;
            s1 += e;
        }
        #pragma unroll
        for (int q = HP; q < DEG; ++q) {
            float e = erow[p][ntq[q]];
            T[pp][q] = e;
            s2 += e;
        }
        a[pp] = (p < dsi) ? __builtin_amdgcn_rcpf(s1 + s2) * 10.0f : 0.0f;
    }

    // ---- 5 Sinkhorn iterations on the scale vectors only ----
    #pragma unroll 1
    for (int it = 0; it < NUM_STEPS; ++it) {
        // column phase: split 3+2 partial chains, combine via DPP
        float part[DEG];
        #pragma unroll
        for (int q = 0; q < DEG; ++q) {
            float c1 = fmaf(T[2][q], a[2], fmaf(T[1][q], a[1], T[0][q] * a[0]));
            float c2 = fmaf(T[4][q], a[4], T[3][q] * a[3]);
            part[q] = c1 + c2;
        }
        #pragma unroll
        for (int q = 0; q < DEG; ++q) {
            float cc = part[q] + pswap(part[q]);   // identical on both lanes
            float bq = bvv[q];
            // masked q: bq==0 -> 0 * rcp(1e-8) == 0 exactly (no predication)
            bvv[q] = bq * __builtin_amdgcn_rcpf(fmaf(bq, cc, 1e-8f));
        }
        // row phase: two 5-deep chains + add
        #pragma unroll
        for (int pp = 0; pp < HP; ++pp) {
            float r1 = T[pp][0] * bvv[0];
            #pragma unroll
            for (int q = 1; q < HP; ++q) r1 = fmaf(T[pp][q], bvv[q], r1);
            float r2 = T[pp][HP] * bvv[HP];
            #pragma unroll
            for (int q = HP + 1; q < DEG; ++q) r2 = fmaf(T[pp][q], bvv[q], r2);
            float r = r1 + r2;
            float ap = a[pp];
            // masked row: ap==0 and r==0 -> 0 * rcp(1e-8) == 0 exactly
            a[pp] = ap * __builtin_amdgcn_rcpf(fmaf(ap, r, 1e-8f));
        }
    }

    // ---- argmax per own row over T*b (first max), cost gather from LDS ----
    float cpart = 0.f;
    #pragma unroll
    for (int pp = 0; pp < HP; ++pp) {
        int p = h * HP + pp;
        if (p < dsi) {
            float best = T[pp][0] * bvv[0];   // q=0 always valid (deg>=1)
            int   bc   = ntq[0];
            #pragma unroll
            for (int q = 1; q < DEG; ++q) {
                float vq = T[pp][q] * bvv[q];
                if (vq > best) { best = vq; bc = ntq[q]; }
            }
            cpart += srow[p][bc];
        }
    }
    float cost = cpart + pswap(cpart);           // identical on both lanes

    float M = (float)((dsi > dtj) ? dsi : dtj);
    float simv = srow[DEG][j];
    float v = fmaf(cost, __builtin_amdgcn_rcpf(1.0f + M), simv);

    // ---- block softmax over j: each pair's v appears twice -> sum * 0.5 ----
    float wm = v;
    #pragma unroll
    for (int off = 32; off; off >>= 1) wm = fmaxf(wm, __shfl_xor(wm, off));
    int wsl = tid >> 6;
    if ((tid & 63) == 0) smax[wsl] = wm;
    __syncthreads();
    float bm = fmaxf(fmaxf(smax[0], smax[1]), fmaxf(smax[2], smax[3]));
    float e = __expf(v - bm);
    float wsum = e;
    #pragma unroll
    for (int off = 32; off; off >>= 1) wsum += __shfl_xor(wsum, off);
    if ((tid & 63) == 0) ssum[wsl] = wsum;
    __syncthreads();
    float bs = (ssum[0] + ssum[1] + ssum[2] + ssum[3]) * 0.5f;

    if (h == 0) out[(size_t)gs * NN + j] = e * __builtin_amdgcn_rcpf(bs);
}

// ---------------------------------------------------------------------------
extern "C" void kernel_launch(void* const* d_in, const int* in_sizes, int n_in,
                              void* d_out, int out_size, void* d_ws, size_t ws_size,
                              hipStream_t stream) {
    (void)in_sizes; (void)n_in; (void)out_size; (void)d_ws; (void)ws_size;
    const float* x_s  = (const float*)d_in[0];
    const int*   ei_s = (const int*)  d_in[1];
    const float* x_t  = (const float*)d_in[3];
    const int*   ei_t = (const int*)  d_in[4];
    float* out = (float*)d_out;

    const int* dst_s = ei_s + NB * NN * DEG;   // second row of edge_index
    const int* dst_t = ei_t + NB * NN * DEG;

    hipLaunchKernelGGL(fused_kernel, dim3(NB * NN), dim3(256), 0, stream,
                       x_s, x_t, dst_s, dst_t, out);
}

// Round 10
// 23.829 us; speedup vs baseline: 1.2422x; 1.0258x over previous
//
#include <hip/hip_runtime.h>
#include <stdint.h>
#include <math.h>

#define NB 8
#define NN 128
#define NC 64
#define DEG 10
#define HP (DEG / 2)
#define NUM_STEPS 5

// DPP lane swaps within a quad (pure VALU, no LDS pipe, convergent callers).
__device__ __forceinline__ float pswap(float x) {   // lanes 2k <-> 2k+1
    return __int_as_float(__builtin_amdgcn_update_dpp(
        0, __float_as_int(x), 0xB1, 0xF, 0xF, false));
}
__device__ __forceinline__ float pswap2(float x) {  // quad_perm [2,3,0,1]
    return __int_as_float(__builtin_amdgcn_update_dpp(
        0, __float_as_int(x), 0x4E, 0xF, 0xF, false));
}

// ---------------------------------------------------------------------------
// Single fused kernel. Block = (b,i), 256 threads.
//
// SIM phase (register-tiled to halve LDS reads): thread (jp = tid>>2,
// qh = tid&3) owns a QUARTER (16 ch) of x_t rows 2jp and 2jp+1 (8 float4 =
// 32 VGPR) and reads each xsl[r] quarter ONCE (4 ds_read_b128), FMA-ing it
// against both columns -> 44 ds_read_b128/thread instead of 88, same FMAs.
// Quarter sums combined with a 2-step DPP butterfly (xor1, xor2) —
// deterministic tree, identical on all 4 lanes; qh==0/1 write cols 2jp/2jp+1.
// Rows p>=dsi of erow are ZEROED; erow has a zero 129th column -> the
// T-gather needs no masking (exact zeros by construction).
//
// SINKHORN phase (lane-pair mapping, unchanged): j = tid>>1, h = tid&1;
// rank-factored S[p][q] == T[p][q]*a[p]*b[q], T = exp(S_hat) (exp monotone +
// row-softmax normalizes => max-subtraction unnecessary; |sim| <~ 45 keeps
// products finite). Thread h owns rows h*5..h*5+4; column sums split p-wise,
// combined via DPP; b/a updates unpredicated (masked lanes self-preserve:
// bq==0 -> 0*rcp(1e-8)==0; invalid row: ap==0,r==0 -> 0). fmaf chains split
// into half-chains (depth ~halved). argmax_q S == argmax_q T*b (a>0
// const/row); q=0 always valid (deg>=1), valid entries strictly positive ->
// masked (zero) slots never win. Masked entries stay EXACT zeros.
// ---------------------------------------------------------------------------
__global__ __launch_bounds__(256, 4) void fused_kernel(
    const float* __restrict__ xs, const float* __restrict__ xt,
    const int* __restrict__ dst_s, const int* __restrict__ dst_t,
    float* __restrict__ out)
{
    __shared__ float  srow[DEG + 1][NN];    // 0..9 neighbor sim rows; 10 self
    __shared__ float  erow[DEG][NN + 1];    // exp rows; col NN is the zero col
    __shared__ float4 xsl[DEG + 1][NC / 4];
    __shared__ float  smax[4], ssum[4];

    const int bi  = blockIdx.x;
    const int b   = bi >> 7, i = bi & 127;
    const int tid = threadIdx.x;
    const int gs  = b * NN + i;

    // ---- s-side neighbor mask (block-uniform) ----
    unsigned long long slo = 0ull, shi = 0ull;
    #pragma unroll
    for (int k = 0; k < DEG; ++k) {
        int d = dst_s[gs * DEG + k] & (NN - 1);
        if (d < 64) slo |= 1ull << d; else shi |= 1ull << (d - 64);
    }
    const int dsi = __popcll(slo) + __popcll(shi);

    // ---- sim-phase mapping: quarter-row, two columns per thread ----
    const int qh = tid & 3;                  // quarter id
    const int jp = tid >> 2;                 // column pair 0..63
    const int c0 = 2 * jp;                   // owned columns c0, c0+1
    const float4* xt0 = (const float4*)(xt + (size_t)(b * NN + c0)     * NC) + qh * 4;
    const float4* xt1 = (const float4*)(xt + (size_t)(b * NN + c0 + 1) * NC) + qh * 4;
    float4 xv0[4], xv1[4];
    #pragma unroll
    for (int k = 0; k < 4; ++k) { xv0[k] = xt0[k]; xv1[k] = xt1[k]; }

    // ---- zero column of erow ----
    if (tid < DEG) erow[tid][NN] = 0.0f;

    // ---- stage x_s rows into LDS: threads 0..175, row = tid>>4, k = tid&15 ----
    if (tid < (DEG + 1) * 16) {
        int r = tid >> 4, k = tid & 15;
        int node = i;                        // r==10 -> self row
        if (r < DEG) {
            unsigned long long lo = slo, hi = shi; int sel = 0;
            #pragma unroll
            for (int q = 0; q < DEG; ++q) {  // static walk, scalar select
                int t;
                if (lo)      { t = __builtin_ctzll(lo);      lo &= lo - 1ull; }
                else if (hi) { t = 64 + __builtin_ctzll(hi); hi &= hi - 1ull; }
                else t = 0;
                if (q == r) sel = t;
            }
            node = sel;
        }
        if (r == DEG || r < dsi)
            xsl[r][k] = ((const float4*)(xs + (size_t)(b * NN + node) * NC))[k];
    }

    // ---- t-side neighbor list for sinkhorn pair j = tid>>1 ----
    const int j = tid >> 1, h = tid & 1;
    const int gt = b * NN + j;
    unsigned long long tlo = 0ull, thi = 0ull;
    #pragma unroll
    for (int k = 0; k < DEG; ++k) {
        int d = dst_t[gt * DEG + k] & (NN - 1);
        if (d < 64) tlo |= 1ull << d; else thi |= 1ull << (d - 64);
    }
    const int dtj = __popcll(tlo) + __popcll(thi);
    int ntq[DEG];
    {
        unsigned long long lo = tlo, hi = thi;
        #pragma unroll
        for (int q = 0; q < DEG; ++q) {      // static-indexed writes
            int t;
            if (lo)      { t = __builtin_ctzll(lo);      lo &= lo - 1ull; }
            else if (hi) { t = 64 + __builtin_ctzll(hi); hi &= hi - 1ull; }
            else t = 0;
            ntq[q] = (q < dtj) ? t : NN;     // invalid -> zero column
        }
    }
    __syncthreads();

    // ---- sim dots: 4 xsl-quarter reads per row, FMA vs both columns ----
    #pragma unroll
    for (int r = 0; r <= DEG; ++r) {
        if (r == DEG || r < dsi) {           // wave-uniform (dsi block-uniform)
            float a0 = 0.f, a1 = 0.f;
            #pragma unroll
            for (int k = 0; k < 4; ++k) {
                float4 s4 = xsl[r][qh * 4 + k];
                a0 += s4.x * xv0[k].x + s4.y * xv0[k].y + s4.z * xv0[k].z + s4.w * xv0[k].w;
                a1 += s4.x * xv1[k].x + s4.y * xv1[k].y + s4.z * xv1[k].z + s4.w * xv1[k].w;
            }
            // 4-lane butterfly: all lanes end with the full deterministic sum
            a0 += pswap(a0);  a0 += pswap2(a0);
            a1 += pswap(a1);  a1 += pswap2(a1);
            float vv = (qh & 1) ? a1 : a0;
            int   cc = c0 + (qh & 1);
            if (qh < 2) {
                srow[r][cc] = vv;
                if (r < DEG) erow[r][cc] = __expf(vv);
            }
        } else {
            if (qh < 2) erow[r][c0 + (qh & 1)] = 0.0f;
        }
    }
    __syncthreads();

    // ---- gather own half of T (unmasked: zeros by construction) ----
    float T[HP][DEG];
    float a[HP], bvv[DEG];
    #pragma unroll
    for (int q = 0; q < DEG; ++q) bvv[q] = (q < dtj) ? 1.0f : 0.0f;

    #pragma unroll
    for (int pp = 0; pp < HP; ++pp) {
        int p = h * HP + pp;
        float s1 = 0.f, s2 = 0.f;            // split sum: depth ~5 not 10
        #pragma unroll
        for (int q = 0; q < HP; ++q) {
            float e = erow[p][ntq[q]];
            T[pp][q] = e;
            s1 += e;
        }
        #pragma unroll
        for (int q = HP; q < DEG; ++q) {
            float e = erow[p][ntq[q]];
            T[pp][q] = e;
            s2 += e;
        }
        a[pp] = (p < dsi) ? __builtin_amdgcn_rcpf(s1 + s2) * 10.0f : 0.0f;
    }

    // ---- 5 Sinkhorn iterations on the scale vectors only ----
    #pragma unroll 1
    for (int it = 0; it < NUM_STEPS; ++it) {
        // column phase: split 3+2 partial chains, combine via DPP
        float part[DEG];
        #pragma unroll
        for (int q = 0; q < DEG; ++q) {
            float cA = fmaf(T[2][q], a[2], fmaf(T[1][q], a[1], T[0][q] * a[0]));
            float cB = fmaf(T[4][q], a[4], T[3][q] * a[3]);
            part[q] = cA + cB;
        }
        #pragma unroll
        for (int q = 0; q < DEG; ++q) {
            float cc = part[q] + pswap(part[q]);   // identical on both lanes
            float bq = bvv[q];
            // masked q: bq==0 -> 0 * rcp(1e-8) == 0 exactly (no predication)
            bvv[q] = bq * __builtin_amdgcn_rcpf(fmaf(bq, cc, 1e-8f));
        }
        // row phase: two 5-deep chains + add
        #pragma unroll
        for (int pp = 0; pp < HP; ++pp) {
            float r1 = T[pp][0] * bvv[0];
            #pragma unroll
            for (int q = 1; q < HP; ++q) r1 = fmaf(T[pp][q], bvv[q], r1);
            float r2 = T[pp][HP] * bvv[HP];
            #pragma unroll
            for (int q = HP + 1; q < DEG; ++q) r2 = fmaf(T[pp][q], bvv[q], r2);
            float r = r1 + r2;
            float ap = a[pp];
            // masked row: ap==0 and r==0 -> 0 * rcp(1e-8) == 0 exactly
            a[pp] = ap * __builtin_amdgcn_rcpf(fmaf(ap, r, 1e-8f));
        }
    }

    // ---- argmax per own row over T*b (first max), cost gather from LDS ----
    float cpart = 0.f;
    #pragma unroll
    for (int pp = 0; pp < HP; ++pp) {
        int p = h * HP + pp;
        if (p < dsi) {
            float best = T[pp][0] * bvv[0];   // q=0 always valid (deg>=1)
            int   bc   = ntq[0];
            #pragma unroll
            for (int q = 1; q < DEG; ++q) {
                float vq = T[pp][q] * bvv[q];
                if (vq > best) { best = vq; bc = ntq[q]; }
            }
            cpart += srow[p][bc];
        }
    }
    float cost = cpart + pswap(cpart);           // identical on both lanes

    float M = (float)((dsi > dtj) ? dsi : dtj);
    float simv = srow[DEG][j];
    float v = fmaf(cost, __builtin_amdgcn_rcpf(1.0f + M), simv);

    // ---- block softmax over j: each pair's v appears twice -> sum * 0.5 ----
    float wm = v;
    #pragma unroll
    for (int off = 32; off; off >>= 1) wm = fmaxf(wm, __shfl_xor(wm, off));
    int wsl = tid >> 6;
    if ((tid & 63) == 0) smax[wsl] = wm;
    __syncthreads();
    float bm = fmaxf(fmaxf(smax[0], smax[1]), fmaxf(smax[2], smax[3]));
    float e = __expf(v - bm);
    float wsum = e;
    #pragma unroll
    for (int off = 32; off; off >>= 1) wsum += __shfl_xor(wsum, off);
    if ((tid & 63) == 0) ssum[wsl] = wsum;
    __syncthreads();
    float bs = (ssum[0] + ssum[1] + ssum[2] + ssum[3]) * 0.5f;

    if (h == 0) out[(size_t)gs * NN + j] = e * __builtin_amdgcn_rcpf(bs);
}

// ---------------------------------------------------------------------------
extern "C" void kernel_launch(void* const* d_in, const int* in_sizes, int n_in,
                              void* d_out, int out_size, void* d_ws, size_t ws_size,
                              hipStream_t stream) {
    (void)in_sizes; (void)n_in; (void)out_size; (void)d_ws; (void)ws_size;
    const float* x_s  = (const float*)d_in[0];
    const int*   ei_s = (const int*)  d_in[1];
    const float* x_t  = (const float*)d_in[3];
    const int*   ei_t = (const int*)  d_in[4];
    float* out = (float*)d_out;

    const int* dst_s = ei_s + NB * NN * DEG;   // second row of edge_index
    const int* dst_t = ei_t + NB * NN * DEG;

    hipLaunchKernelGGL(fused_kernel, dim3(NB * NN), dim3(256), 0, stream,
                       x_s, x_t, dst_s, dst_t, out);
}

// Round 11
// 23.431 us; speedup vs baseline: 1.2633x; 1.0170x over previous
//
#include <hip/hip_runtime.h>
#include <stdint.h>
#include <math.h>

#define NB 8
#define NN 128
#define NC 64
#define DEG 10
#define HP (DEG / 2)
#define NUM_STEPS 5

// DPP lane swaps within a quad (pure VALU, no LDS pipe, convergent callers).
__device__ __forceinline__ float pswap(float x) {   // lanes 2k <-> 2k+1
    return __int_as_float(__builtin_amdgcn_update_dpp(
        0, __float_as_int(x), 0xB1, 0xF, 0xF, false));
}
__device__ __forceinline__ float pswap2(float x) {  // quad_perm [2,3,0,1]
    return __int_as_float(__builtin_amdgcn_update_dpp(
        0, __float_as_int(x), 0x4E, 0xF, 0xF, false));
}

// ---------------------------------------------------------------------------
// Single fused kernel. Block = (b,i), 256 threads.
//
// SIM phase (register-tiled): thread (jp = tid>>2, qh = tid&3) owns a QUARTER
// of x_t rows 2jp, 2jp+1; reads each xsl[r] quarter once (broadcast reads —
// all column-pairs share addresses), FMAs vs both columns; 2-step DPP
// butterfly; qh==0/1 write cols 2jp/2jp+1 of erow (exp). NO srow staging:
// raw sim values are recovered later as ln(T) from registers. Self row kept
// in ssim[] for the epilogue. Rows p>=dsi of erow ZEROED; zero 129th column
// -> T-gather needs no masking (exact zeros by construction).
//
// SINKHORN phase: j = tid>>1, h = tid&1; rank-factored S[p][q] ==
// T[p][q]*a[p]*b[q], T = exp(S_hat) (exp monotone + row-softmax normalizes
// => max-subtraction unnecessary; |sim| <~ 45 keeps products finite).
// Thread h owns rows h*5..h*5+4; col sums split p-wise, combined via DPP;
// b/a updates unpredicated (masked lanes self-preserve: 0*rcp(1e-8)==0).
// argmax_q S == argmax_q T*b (a>0 const/row); q=0 always valid (deg>=1),
// valid entries strictly positive -> masked (zero) slots never win.
// cost contribution = srow value = ln(T[best]) via __logf (roundtrip err
// ~5e-6, 3 orders below bf16 output granularity).
// Tail: ONE barrier — per-wave (max, sum-of-exp), block combine with
// ssum[w]*exp(smax[w]-bm); each pair's v appears twice -> *0.5.
// ---------------------------------------------------------------------------
__global__ __launch_bounds__(256, 4) void fused_kernel(
    const float* __restrict__ xs, const float* __restrict__ xt,
    const int* __restrict__ dst_s, const int* __restrict__ dst_t,
    float* __restrict__ out)
{
    __shared__ float  ssim[NN];             // self sim row (for epilogue)
    __shared__ float  erow[DEG][NN + 1];    // exp rows; col NN is the zero col
    __shared__ float4 xsl[DEG + 1][NC / 4];
    __shared__ float  smax[4], ssum[4];

    const int bi  = blockIdx.x;
    const int b   = bi >> 7, i = bi & 127;
    const int tid = threadIdx.x;
    const int gs  = b * NN + i;

    // ---- s-side neighbor mask (block-uniform) ----
    unsigned long long slo = 0ull, shi = 0ull;
    #pragma unroll
    for (int k = 0; k < DEG; ++k) {
        int d = dst_s[gs * DEG + k] & (NN - 1);
        if (d < 64) slo |= 1ull << d; else shi |= 1ull << (d - 64);
    }
    const int dsi = __popcll(slo) + __popcll(shi);

    // ---- sim-phase mapping: quarter-row, two columns per thread ----
    const int qh = tid & 3;                  // quarter id
    const int jp = tid >> 2;                 // column pair 0..63
    const int c0 = 2 * jp;                   // owned columns c0, c0+1
    const float4* xt0 = (const float4*)(xt + (size_t)(b * NN + c0)     * NC) + qh * 4;
    const float4* xt1 = (const float4*)(xt + (size_t)(b * NN + c0 + 1) * NC) + qh * 4;
    float4 xv0[4], xv1[4];
    #pragma unroll
    for (int k = 0; k < 4; ++k) { xv0[k] = xt0[k]; xv1[k] = xt1[k]; }

    // ---- zero column of erow ----
    if (tid < DEG) erow[tid][NN] = 0.0f;

    // ---- stage x_s rows into LDS: threads 0..175, row = tid>>4, k = tid&15 ----
    if (tid < (DEG + 1) * 16) {
        int r = tid >> 4, k = tid & 15;
        int node = i;                        // r==10 -> self row
        if (r < DEG) {
            unsigned long long lo = slo, hi = shi; int sel = 0;
            #pragma unroll
            for (int q = 0; q < DEG; ++q) {  // static walk, scalar select
                int t;
                if (lo)      { t = __builtin_ctzll(lo);      lo &= lo - 1ull; }
                else if (hi) { t = 64 + __builtin_ctzll(hi); hi &= hi - 1ull; }
                else t = 0;
                if (q == r) sel = t;
            }
            node = sel;
        }
        if (r == DEG || r < dsi)
            xsl[r][k] = ((const float4*)(xs + (size_t)(b * NN + node) * NC))[k];
    }

    // ---- t-side neighbor list for sinkhorn pair j = tid>>1 ----
    const int j = tid >> 1, h = tid & 1;
    const int gt = b * NN + j;
    unsigned long long tlo = 0ull, thi = 0ull;
    #pragma unroll
    for (int k = 0; k < DEG; ++k) {
        int d = dst_t[gt * DEG + k] & (NN - 1);
        if (d < 64) tlo |= 1ull << d; else thi |= 1ull << (d - 64);
    }
    const int dtj = __popcll(tlo) + __popcll(thi);
    int ntq[DEG];
    {
        unsigned long long lo = tlo, hi = thi;
        #pragma unroll
        for (int q = 0; q < DEG; ++q) {      // static-indexed writes
            int t;
            if (lo)      { t = __builtin_ctzll(lo);      lo &= lo - 1ull; }
            else if (hi) { t = 64 + __builtin_ctzll(hi); hi &= hi - 1ull; }
            else t = 0;
            ntq[q] = (q < dtj) ? t : NN;     // invalid -> zero column
        }
    }
    __syncthreads();

    // ---- sim dots: 4 xsl-quarter broadcast reads per row, 2 columns ----
    #pragma unroll
    for (int r = 0; r <= DEG; ++r) {
        if (r == DEG || r < dsi) {           // wave-uniform (dsi block-uniform)
            float a0 = 0.f, a1 = 0.f;
            #pragma unroll
            for (int k = 0; k < 4; ++k) {
                float4 s4 = xsl[r][qh * 4 + k];
                a0 += s4.x * xv0[k].x + s4.y * xv0[k].y + s4.z * xv0[k].z + s4.w * xv0[k].w;
                a1 += s4.x * xv1[k].x + s4.y * xv1[k].y + s4.z * xv1[k].z + s4.w * xv1[k].w;
            }
            // 4-lane butterfly: all lanes end with the full deterministic sum
            a0 += pswap(a0);  a0 += pswap2(a0);
            a1 += pswap(a1);  a1 += pswap2(a1);
            float vv = (qh & 1) ? a1 : a0;
            int   cc = c0 + (qh & 1);
            if (qh < 2) {
                if (r < DEG) erow[r][cc] = __expf(vv);
                else         ssim[cc] = vv;
            }
        } else {
            if (qh < 2) erow[r][c0 + (qh & 1)] = 0.0f;
        }
    }
    __syncthreads();

    // ---- gather own half of T (unmasked: zeros by construction) ----
    float T[HP][DEG];
    float a[HP], bvv[DEG];
    #pragma unroll
    for (int q = 0; q < DEG; ++q) bvv[q] = (q < dtj) ? 1.0f : 0.0f;

    #pragma unroll
    for (int pp = 0; pp < HP; ++pp) {
        int p = h * HP + pp;
        float s1 = 0.f, s2 = 0.f;            // split sum: depth ~5 not 10
        #pragma unroll
        for (int q = 0; q < HP; ++q) {
            float e = erow[p][ntq[q]];
            T[pp][q] = e;
            s1 += e;
        }
        #pragma unroll
        for (int q = HP; q < DEG; ++q) {
            float e = erow[p][ntq[q]];
            T[pp][q] = e;
            s2 += e;
        }
        a[pp] = (p < dsi) ? __builtin_amdgcn_rcpf(s1 + s2) * 10.0f : 0.0f;
    }

    // ---- 5 Sinkhorn iterations on the scale vectors only ----
    #pragma unroll 1
    for (int it = 0; it < NUM_STEPS; ++it) {
        // column phase: split 3+2 partial chains, combine via DPP
        float part[DEG];
        #pragma unroll
        for (int q = 0; q < DEG; ++q) {
            float cA = fmaf(T[2][q], a[2], fmaf(T[1][q], a[1], T[0][q] * a[0]));
            float cB = fmaf(T[4][q], a[4], T[3][q] * a[3]);
            part[q] = cA + cB;
        }
        #pragma unroll
        for (int q = 0; q < DEG; ++q) {
            float cc = part[q] + pswap(part[q]);   // identical on both lanes
            float bq = bvv[q];
            // masked q: bq==0 -> 0 * rcp(1e-8) == 0 exactly (no predication)
            bvv[q] = bq * __builtin_amdgcn_rcpf(fmaf(bq, cc, 1e-8f));
        }
        // row phase: two 5-deep chains + add
        #pragma unroll
        for (int pp = 0; pp < HP; ++pp) {
            float r1 = T[pp][0] * bvv[0];
            #pragma unroll
            for (int q = 1; q < HP; ++q) r1 = fmaf(T[pp][q], bvv[q], r1);
            float r2 = T[pp][HP] * bvv[HP];
            #pragma unroll
            for (int q = HP + 1; q < DEG; ++q) r2 = fmaf(T[pp][q], bvv[q], r2);
            float r = r1 + r2;
            float ap = a[pp];
            // masked row: ap==0 and r==0 -> 0 * rcp(1e-8) == 0 exactly
            a[pp] = ap * __builtin_amdgcn_rcpf(fmaf(ap, r, 1e-8f));
        }
    }

    // ---- argmax per own row over T*b; cost = ln(T[best]) (no LDS gather) ----
    float cpart = 0.f;
    #pragma unroll
    for (int pp = 0; pp < HP; ++pp) {
        int p = h * HP + pp;
        if (p < dsi) {
            float best = T[pp][0] * bvv[0];   // q=0 always valid (deg>=1)
            float bT   = T[pp][0];
            #pragma unroll
            for (int q = 1; q < DEG; ++q) {
                float vq = T[pp][q] * bvv[q];
                if (vq > best) { best = vq; bT = T[pp][q]; }
            }
            cpart += __logf(bT);              // == srow value (roundtrip ~5e-6)
        }
    }
    float cost = cpart + pswap(cpart);           // identical on both lanes

    float M = (float)((dsi > dtj) ? dsi : dtj);
    float simv = ssim[j];
    float v = fmaf(cost, __builtin_amdgcn_rcpf(1.0f + M), simv);

    // ---- one-barrier block softmax over j (each pair's v counted twice) ----
    float wm = v;
    #pragma unroll
    for (int off = 32; off; off >>= 1) wm = fmaxf(wm, __shfl_xor(wm, off));
    float ew = __expf(v - wm);
    float ws = ew;
    #pragma unroll
    for (int off = 32; off; off >>= 1) ws += __shfl_xor(ws, off);
    int wsl = tid >> 6;
    if ((tid & 63) == 0) { smax[wsl] = wm; ssum[wsl] = ws; }
    __syncthreads();
    float bm = fmaxf(fmaxf(smax[0], smax[1]), fmaxf(smax[2], smax[3]));
    float bs = (ssum[0] * __expf(smax[0] - bm) + ssum[1] * __expf(smax[1] - bm) +
                ssum[2] * __expf(smax[2] - bm) + ssum[3] * __expf(smax[3] - bm)) * 0.5f;
    float e = ew * __expf(wm - bm);

    if (h == 0) out[(size_t)gs * NN + j] = e * __builtin_amdgcn_rcpf(bs);
}

// ---------------------------------------------------------------------------
extern "C" void kernel_launch(void* const* d_in, const int* in_sizes, int n_in,
                              void* d_out, int out_size, void* d_ws, size_t ws_size,
                              hipStream_t stream) {
    (void)in_sizes; (void)n_in; (void)out_size; (void)d_ws; (void)ws_size;
    const float* x_s  = (const float*)d_in[0];
    const int*   ei_s = (const int*)  d_in[1];
    const float* x_t  = (const float*)d_in[3];
    const int*   ei_t = (const int*)  d_in[4];
    float* out = (float*)d_out;

    const int* dst_s = ei_s + NB * NN * DEG;   // second row of edge_index
    const int* dst_t = ei_t + NB * NN * DEG;

    hipLaunchKernelGGL(fused_kernel, dim3(NB * NN), dim3(256), 0, stream,
                       x_s, x_t, dst_s, dst_t, out);
}

// Round 12
// 22.391 us; speedup vs baseline: 1.3220x; 1.0465x over previous
//
#include <hip/hip_runtime.h>
#include <stdint.h>
#include <math.h>

#define NB 8
#define NN 128
#define NC 64
#define DEG 10
#define HP (DEG / 2)
#define NUM_STEPS 5

// DPP lane swaps within a quad (pure VALU, no LDS pipe, convergent callers).
__device__ __forceinline__ float pswap(float x) {   // lanes 2k <-> 2k+1
    return __int_as_float(__builtin_amdgcn_update_dpp(
        0, __float_as_int(x), 0xB1, 0xF, 0xF, false));
}
__device__ __forceinline__ float pswap2(float x) {  // quad_perm [2,3,0,1]
    return __int_as_float(__builtin_amdgcn_update_dpp(
        0, __float_as_int(x), 0x4E, 0xF, 0xF, false));
}
// DPP with 0-fill out-of-bounds: safe for SUM reductions (adds 0).
template<int C>
__device__ __forceinline__ float dpp0(float x) {
    return __int_as_float(__builtin_amdgcn_update_dpp(
        0, __float_as_int(x), C, 0xF, 0xF, true));
}

// ---------------------------------------------------------------------------
// Single fused kernel. Block = (b,i), 256 threads.
//
// SIM phase (register-tiled): thread (jp = tid>>2, qh = tid&3) owns a QUARTER
// of x_t rows 2jp, 2jp+1; broadcast-reads each xsl[r] quarter, FMAs vs both
// columns; 2-step DPP butterfly; qh==0/1 write cols 2jp/2jp+1.
// exp(sim) stored TRANSPOSED: ecol[col][slot], slot(r) = r + (r>=5 ? 3 : 0)
// (rows 0..4 -> slots 0..4, rows 5..9 -> slots 8..12; inner dim 20 floats
// keeps 16B alignment for b128 at slot 0 and 8, banks spread over 8
// residues). Rows p>=dsi zeroed; col NN all-zero -> T-gather needs no mask.
// Raw sim values recovered later as ln(T); self row kept in ssim[].
//
// SINKHORN phase: j = tid>>1, h = tid&1; rank-factored S[p][q] ==
// T[p][q]*a[p]*b[q], T = exp(S_hat) (exp monotone + row-softmax normalizes
// => max-subtraction unnecessary; |sim| <~ 45 keeps products finite).
// T-gather per q: ONE ds_read_b128 + ONE ds_read_b32 from ecol[ntq[q]]
// (20 LDS ops instead of 50). Thread h owns rows h*5..h*5+4; col sums split
// p-wise, combined via DPP; b/a updates unpredicated (masked lanes
// self-preserve: 0*rcp(1e-8)==0). argmax_q S == argmax_q T*b (a>0
// const/row); q=0 always valid (deg>=1), valid entries strictly positive ->
// masked (zero) slots never win. cost = ln(T[best]) via __logf (roundtrip
// ~5e-6, far below bf16 output granularity).
// Tail: ONE barrier — wave max via shfl butterfly (all lanes), wave sum via
// DPP shr/bcast tree (lane 63 writes); block combine ssum[w]*exp(smax[w]-bm);
// each pair's v appears twice -> *0.5.
// ---------------------------------------------------------------------------
__global__ __launch_bounds__(256, 4) void fused_kernel(
    const float* __restrict__ xs, const float* __restrict__ xt,
    const int* __restrict__ dst_s, const int* __restrict__ dst_t,
    float* __restrict__ out)
{
    __shared__ float  ssim[NN];              // self sim row (for epilogue)
    __shared__ float  ecol[NN + 1][20];      // transposed exp rows; col NN zero
    __shared__ float4 xsl[DEG + 1][NC / 4];
    __shared__ float  smax[4], ssum[4];

    const int bi  = blockIdx.x;
    const int b   = bi >> 7, i = bi & 127;
    const int tid = threadIdx.x;
    const int gs  = b * NN + i;

    // ---- s-side neighbor mask (block-uniform) ----
    unsigned long long slo = 0ull, shi = 0ull;
    #pragma unroll
    for (int k = 0; k < DEG; ++k) {
        int d = dst_s[gs * DEG + k] & (NN - 1);
        if (d < 64) slo |= 1ull << d; else shi |= 1ull << (d - 64);
    }
    const int dsi = __popcll(slo) + __popcll(shi);

    // ---- sim-phase mapping: quarter-row, two columns per thread ----
    const int qh = tid & 3;                  // quarter id
    const int jp = tid >> 2;                 // column pair 0..63
    const int c0 = 2 * jp;                   // owned columns c0, c0+1
    const float4* xt0 = (const float4*)(xt + (size_t)(b * NN + c0)     * NC) + qh * 4;
    const float4* xt1 = (const float4*)(xt + (size_t)(b * NN + c0 + 1) * NC) + qh * 4;
    float4 xv0[4], xv1[4];
    #pragma unroll
    for (int k = 0; k < 4; ++k) { xv0[k] = xt0[k]; xv1[k] = xt1[k]; }

    // ---- zero column of ecol (slots 0..12 cover all read slots) ----
    if (tid < 13) ecol[NN][tid] = 0.0f;

    // ---- stage x_s rows into LDS: threads 0..175, row = tid>>4, k = tid&15 ----
    if (tid < (DEG + 1) * 16) {
        int r = tid >> 4, k = tid & 15;
        int node = i;                        // r==10 -> self row
        if (r < DEG) {
            unsigned long long lo = slo, hi = shi; int sel = 0;
            #pragma unroll
            for (int q = 0; q < DEG; ++q) {  // static walk, scalar select
                int t;
                if (lo)      { t = __builtin_ctzll(lo);      lo &= lo - 1ull; }
                else if (hi) { t = 64 + __builtin_ctzll(hi); hi &= hi - 1ull; }
                else t = 0;
                if (q == r) sel = t;
            }
            node = sel;
        }
        if (r == DEG || r < dsi)
            xsl[r][k] = ((const float4*)(xs + (size_t)(b * NN + node) * NC))[k];
    }

    // ---- t-side neighbor list for sinkhorn pair j = tid>>1 (int2 loads) ----
    const int j = tid >> 1, h = tid & 1;
    const int gt = b * NN + j;
    unsigned long long tlo = 0ull, thi = 0ull;
    {
        const int2* dt2 = (const int2*)(dst_t + (size_t)gt * DEG);  // 40B rows, 8B-aligned
        int2 w0 = dt2[0], w1 = dt2[1], w2 = dt2[2], w3 = dt2[3], w4 = dt2[4];
        int dd[DEG] = { w0.x, w0.y, w1.x, w1.y, w2.x, w2.y, w3.x, w3.y, w4.x, w4.y };
        #pragma unroll
        for (int k = 0; k < DEG; ++k) {      // static-indexed reads of dd
            int dm = dd[k] & (NN - 1);
            if (dm < 64) tlo |= 1ull << dm; else thi |= 1ull << (dm - 64);
        }
    }
    const int dtj = __popcll(tlo) + __popcll(thi);
    int ntq[DEG];
    {
        unsigned long long lo = tlo, hi = thi;
        #pragma unroll
        for (int q = 0; q < DEG; ++q) {      // static-indexed writes
            int t;
            if (lo)      { t = __builtin_ctzll(lo);      lo &= lo - 1ull; }
            else if (hi) { t = 64 + __builtin_ctzll(hi); hi &= hi - 1ull; }
            else t = 0;
            ntq[q] = (q < dtj) ? t : NN;     // invalid -> zero column
        }
    }
    __syncthreads();

    // ---- sim dots: 4 xsl-quarter broadcast reads per row, 2 columns ----
    #pragma unroll
    for (int r = 0; r <= DEG; ++r) {
        if (r == DEG || r < dsi) {           // wave-uniform (dsi block-uniform)
            float a0 = 0.f, a1 = 0.f;
            #pragma unroll
            for (int k = 0; k < 4; ++k) {
                float4 s4 = xsl[r][qh * 4 + k];
                a0 += s4.x * xv0[k].x + s4.y * xv0[k].y + s4.z * xv0[k].z + s4.w * xv0[k].w;
                a1 += s4.x * xv1[k].x + s4.y * xv1[k].y + s4.z * xv1[k].z + s4.w * xv1[k].w;
            }
            // 4-lane butterfly: all lanes end with the full deterministic sum
            a0 += pswap(a0);  a0 += pswap2(a0);
            a1 += pswap(a1);  a1 += pswap2(a1);
            float vv = (qh & 1) ? a1 : a0;
            int   cc = c0 + (qh & 1);
            if (qh < 2) {
                if (r < DEG) ecol[cc][r + ((r >= HP) ? 3 : 0)] = __expf(vv);
                else         ssim[cc] = vv;
            }
        } else {
            if (qh < 2) ecol[c0 + (qh & 1)][r + ((r >= HP) ? 3 : 0)] = 0.0f;
        }
    }
    __syncthreads();

    // ---- gather own half of T: per q one b128 + one b32 (transposed) ----
    float T[HP][DEG];
    float a[HP], bvv[DEG];
    #pragma unroll
    for (int q = 0; q < DEG; ++q) bvv[q] = (q < dtj) ? 1.0f : 0.0f;

    const int sbase = h << 3;                // h=0 -> slots 0..4; h=1 -> 8..12
    #pragma unroll
    for (int q = 0; q < DEG; ++q) {
        const float* cp = &ecol[ntq[q]][sbase];
        float4 t4 = *(const float4*)cp;      // ds_read_b128 (16B aligned)
        float  te = cp[4];                   // ds_read_b32
        T[0][q] = t4.x; T[1][q] = t4.y; T[2][q] = t4.z; T[3][q] = t4.w; T[4][q] = te;
    }
    #pragma unroll
    for (int pp = 0; pp < HP; ++pp) {
        int p = h * HP + pp;
        float s1 = T[pp][0] + T[pp][1] + T[pp][2] + T[pp][3] + T[pp][4];
        float s2 = T[pp][5] + T[pp][6] + T[pp][7] + T[pp][8] + T[pp][9];
        a[pp] = (p < dsi) ? __builtin_amdgcn_rcpf(s1 + s2) * 10.0f : 0.0f;
    }

    // ---- 5 Sinkhorn iterations on the scale vectors only ----
    #pragma unroll 1
    for (int it = 0; it < NUM_STEPS; ++it) {
        // column phase: split 3+2 partial chains, combine via DPP
        float part[DEG];
        #pragma unroll
        for (int q = 0; q < DEG; ++q) {
            float cA = fmaf(T[2][q], a[2], fmaf(T[1][q], a[1], T[0][q] * a[0]));
            float cB = fmaf(T[4][q], a[4], T[3][q] * a[3]);
            part[q] = cA + cB;
        }
        #pragma unroll
        for (int q = 0; q < DEG; ++q) {
            float cc = part[q] + pswap(part[q]);   // identical on both lanes
            float bq = bvv[q];
            // masked q: bq==0 -> 0 * rcp(1e-8) == 0 exactly (no predication)
            bvv[q] = bq * __builtin_amdgcn_rcpf(fmaf(bq, cc, 1e-8f));
        }
        // row phase: two 5-deep chains + add
        #pragma unroll
        for (int pp = 0; pp < HP; ++pp) {
            float r1 = T[pp][0] * bvv[0];
            #pragma unroll
            for (int q = 1; q < HP; ++q) r1 = fmaf(T[pp][q], bvv[q], r1);
            float r2 = T[pp][HP] * bvv[HP];
            #pragma unroll
            for (int q = HP + 1; q < DEG; ++q) r2 = fmaf(T[pp][q], bvv[q], r2);
            float r = r1 + r2;
            float ap = a[pp];
            // masked row: ap==0 and r==0 -> 0 * rcp(1e-8) == 0 exactly
            a[pp] = ap * __builtin_amdgcn_rcpf(fmaf(ap, r, 1e-8f));
        }
    }

    // ---- argmax per own row over T*b; cost = ln(T[best]) (no LDS gather) ----
    float cpart = 0.f;
    #pragma unroll
    for (int pp = 0; pp < HP; ++pp) {
        int p = h * HP + pp;
        if (p < dsi) {
            float best = T[pp][0] * bvv[0];   // q=0 always valid (deg>=1)
            float bT   = T[pp][0];
            #pragma unroll
            for (int q = 1; q < DEG; ++q) {
                float vq = T[pp][q] * bvv[q];
                if (vq > best) { best = vq; bT = T[pp][q]; }
            }
            cpart += __logf(bT);              // == sim value (roundtrip ~5e-6)
        }
    }
    float cost = cpart + pswap(cpart);           // identical on both lanes

    float M = (float)((dsi > dtj) ? dsi : dtj);
    float simv = ssim[j];
    float v = fmaf(cost, __builtin_amdgcn_rcpf(1.0f + M), simv);

    // ---- one-barrier block softmax over j (each pair's v counted twice) ----
    float wm = v;                                // wave max: all lanes need it
    #pragma unroll
    for (int off = 32; off; off >>= 1) wm = fmaxf(wm, __shfl_xor(wm, off));
    float ew = __expf(v - wm);
    // wave sum via DPP tree (0-fill OOB); total lands on lane 63
    float ws = ew;
    ws += dpp0<0x111>(ws);                       // row_shr:1
    ws += dpp0<0x112>(ws);                       // row_shr:2
    ws += dpp0<0x114>(ws);                       // row_shr:4
    ws += dpp0<0x118>(ws);                       // row_shr:8
    ws += dpp0<0x142>(ws);                       // row_bcast15
    ws += dpp0<0x143>(ws);                       // row_bcast31
    int wsl = tid >> 6;
    if ((tid & 63) == 63) { smax[wsl] = wm; ssum[wsl] = ws; }
    __syncthreads();
    float bm = fmaxf(fmaxf(smax[0], smax[1]), fmaxf(smax[2], smax[3]));
    float bs = (ssum[0] * __expf(smax[0] - bm) + ssum[1] * __expf(smax[1] - bm) +
                ssum[2] * __expf(smax[2] - bm) + ssum[3] * __expf(smax[3] - bm)) * 0.5f;
    float e = ew * __expf(wm - bm);

    if (h == 0) out[(size_t)gs * NN + j] = e * __builtin_amdgcn_rcpf(bs);
}

// ---------------------------------------------------------------------------
extern "C" void kernel_launch(void* const* d_in, const int* in_sizes, int n_in,
                              void* d_out, int out_size, void* d_ws, size_t ws_size,
                              hipStream_t stream) {
    (void)in_sizes; (void)n_in; (void)out_size; (void)d_ws; (void)ws_size;
    const float* x_s  = (const float*)d_in[0];
    const int*   ei_s = (const int*)  d_in[1];
    const float* x_t  = (const float*)d_in[3];
    const int*   ei_t = (const int*)  d_in[4];
    float* out = (float*)d_out;

    const int* dst_s = ei_s + NB * NN * DEG;   // second row of edge_index
    const int* dst_t = ei_t + NB * NN * DEG;

    hipLaunchKernelGGL(fused_kernel, dim3(NB * NN), dim3(256), 0, stream,
                       x_s, x_t, dst_s, dst_t, out);
}

// Round 13
// 21.780 us; speedup vs baseline: 1.3590x; 1.0280x over previous
//
#include <hip/hip_runtime.h>
#include <stdint.h>
#include <math.h>

#define NB 8
#define NN 128
#define NC 64
#define DEG 10
#define HP (DEG / 2)
#define NUM_STEPS 5

typedef float v2f __attribute__((ext_vector_type(2)));

__device__ __forceinline__ v2f mk2(float x, float y) { v2f r; r.x = x; r.y = y; return r; }
__device__ __forceinline__ v2f splat2(float x)       { v2f r; r.x = x; r.y = x; return r; }
__device__ __forceinline__ v2f pfma(v2f a, v2f b, v2f c) {
    return __builtin_elementwise_fma(a, b, c);     // -> v_pk_fma_f32 on gfx950
}

// DPP lane swaps within a quad (pure VALU, no LDS pipe, convergent callers).
__device__ __forceinline__ float pswap(float x) {   // lanes 2k <-> 2k+1
    return __int_as_float(__builtin_amdgcn_update_dpp(
        0, __float_as_int(x), 0xB1, 0xF, 0xF, false));
}
__device__ __forceinline__ float pswap2(float x) {  // quad_perm [2,3,0,1]
    return __int_as_float(__builtin_amdgcn_update_dpp(
        0, __float_as_int(x), 0x4E, 0xF, 0xF, false));
}
// DPP with 0-fill out-of-bounds: safe for SUM reductions (adds 0).
template<int C>
__device__ __forceinline__ float dpp0(float x) {
    return __int_as_float(__builtin_amdgcn_update_dpp(
        0, __float_as_int(x), C, 0xF, 0xF, true));
}

// ---------------------------------------------------------------------------
// Single fused kernel. Block = (b,i), 256 threads. R12 structure + packed
// dual-FP32 (v_pk_fma_f32) on both the sim dots (column pair packed) and the
// Sinkhorn matvecs (q-pairs packed). Packed fma is IEEE-identical per
// component; only reduction association changes (carried ulp class).
//
// SIM phase: thread (jp = tid>>2, qh = tid&3) owns a QUARTER of x_t rows
// 2jp, 2jp+1 packed as v2f xvp[16]; broadcast-reads each xsl[r] quarter,
// 16 packed FMAs per row; 2-step DPP butterfly per component; qh==0/1 write
// cols 2jp/2jp+1. exp(sim) stored TRANSPOSED: ecol[col][slot], slot(r) =
// r + (r>=5 ? 3 : 0) (16B-aligned b128 at slots 0/8). Rows p>=dsi zeroed;
// col NN all-zero -> T-gather needs no mask. Raw sim recovered as ln(T);
// self row in ssim[].
//
// SINKHORN: j = tid>>1, h = tid&1; rank-factored S[p][q] ==
// T[p][q]*a[p]*b[q], T = exp(S_hat) (exp monotone + row-softmax normalizes
// => max-subtraction unnecessary; |sim| <~ 45 keeps products finite).
// T packed by q-pairs at the gather (components come straight from two
// b128 loads -> no extra movs). Thread h owns rows h*5..h*5+4; col sums
// split p-wise, combined via DPP per component; b/a updates unpredicated
// (masked lanes self-preserve: 0*rcp(1e-8)==0). argmax_q S == argmax_q T*b
// (a>0 const/row), visited in exact q order (first-max kept); q=0 always
// valid (deg>=1), valid entries strictly positive -> zero slots never win.
// cost = ln(T[best]) via __logf (roundtrip ~5e-6 << bf16 granularity).
// Tail: ONE barrier — wave max via shfl butterfly, wave sum via DPP
// shr/bcast tree (lane 63 writes); block combine ssum[w]*exp(smax[w]-bm);
// each pair's v appears twice -> *0.5.
// ---------------------------------------------------------------------------
__global__ __launch_bounds__(256, 4) void fused_kernel(
    const float* __restrict__ xs, const float* __restrict__ xt,
    const int* __restrict__ dst_s, const int* __restrict__ dst_t,
    float* __restrict__ out)
{
    __shared__ float  ssim[NN];              // self sim row (for epilogue)
    __shared__ float  ecol[NN + 1][20];      // transposed exp rows; col NN zero
    __shared__ float4 xsl[DEG + 1][NC / 4];
    __shared__ float  smax[4], ssum[4];

    const int bi  = blockIdx.x;
    const int b   = bi >> 7, i = bi & 127;
    const int tid = threadIdx.x;
    const int gs  = b * NN + i;

    // ---- s-side neighbor mask (block-uniform) ----
    unsigned long long slo = 0ull, shi = 0ull;
    #pragma unroll
    for (int k = 0; k < DEG; ++k) {
        int d = dst_s[gs * DEG + k] & (NN - 1);
        if (d < 64) slo |= 1ull << d; else shi |= 1ull << (d - 64);
    }
    const int dsi = __popcll(slo) + __popcll(shi);

    // ---- sim-phase mapping: quarter-row, two columns per thread (packed) ----
    const int qh = tid & 3;                  // quarter id
    const int jp = tid >> 2;                 // column pair 0..63
    const int c0 = 2 * jp;                   // owned columns c0, c0+1
    v2f xvp[16];
    {
        const float4* xt0 = (const float4*)(xt + (size_t)(b * NN + c0)     * NC) + qh * 4;
        const float4* xt1 = (const float4*)(xt + (size_t)(b * NN + c0 + 1) * NC) + qh * 4;
        #pragma unroll
        for (int k = 0; k < 4; ++k) {
            float4 u = xt0[k], w = xt1[k];
            xvp[4 * k + 0] = mk2(u.x, w.x);
            xvp[4 * k + 1] = mk2(u.y, w.y);
            xvp[4 * k + 2] = mk2(u.z, w.z);
            xvp[4 * k + 3] = mk2(u.w, w.w);
        }
    }

    // ---- zero column of ecol (slots 0..12 cover all read slots) ----
    if (tid < 13) ecol[NN][tid] = 0.0f;

    // ---- stage x_s rows into LDS: threads 0..175, row = tid>>4, k = tid&15 ----
    if (tid < (DEG + 1) * 16) {
        int r = tid >> 4, k = tid & 15;
        int node = i;                        // r==10 -> self row
        if (r < DEG) {
            unsigned long long lo = slo, hi = shi; int sel = 0;
            #pragma unroll
            for (int q = 0; q < DEG; ++q) {  // static walk, scalar select
                int t;
                if (lo)      { t = __builtin_ctzll(lo);      lo &= lo - 1ull; }
                else if (hi) { t = 64 + __builtin_ctzll(hi); hi &= hi - 1ull; }
                else t = 0;
                if (q == r) sel = t;
            }
            node = sel;
        }
        if (r == DEG || r < dsi)
            xsl[r][k] = ((const float4*)(xs + (size_t)(b * NN + node) * NC))[k];
    }

    // ---- t-side neighbor list for sinkhorn pair j = tid>>1 (int2 loads) ----
    const int j = tid >> 1, h = tid & 1;
    const int gt = b * NN + j;
    unsigned long long tlo = 0ull, thi = 0ull;
    {
        const int2* dt2 = (const int2*)(dst_t + (size_t)gt * DEG);  // 40B rows, 8B-aligned
        int2 w0 = dt2[0], w1 = dt2[1], w2 = dt2[2], w3 = dt2[3], w4 = dt2[4];
        int dd[DEG] = { w0.x, w0.y, w1.x, w1.y, w2.x, w2.y, w3.x, w3.y, w4.x, w4.y };
        #pragma unroll
        for (int k = 0; k < DEG; ++k) {      // static-indexed reads of dd
            int dm = dd[k] & (NN - 1);
            if (dm < 64) tlo |= 1ull << dm; else thi |= 1ull << (dm - 64);
        }
    }
    const int dtj = __popcll(tlo) + __popcll(thi);
    int ntq[DEG];
    {
        unsigned long long lo = tlo, hi = thi;
        #pragma unroll
        for (int q = 0; q < DEG; ++q) {      // static-indexed writes
            int t;
            if (lo)      { t = __builtin_ctzll(lo);      lo &= lo - 1ull; }
            else if (hi) { t = 64 + __builtin_ctzll(hi); hi &= hi - 1ull; }
            else t = 0;
            ntq[q] = (q < dtj) ? t : NN;     // invalid -> zero column
        }
    }
    __syncthreads();

    // ---- sim dots: 4 xsl-quarter broadcast reads/row, 16 packed FMAs ----
    #pragma unroll
    for (int r = 0; r <= DEG; ++r) {
        if (r == DEG || r < dsi) {           // wave-uniform (dsi block-uniform)
            v2f acc = mk2(0.f, 0.f);
            #pragma unroll
            for (int k = 0; k < 4; ++k) {
                float4 s4 = xsl[r][qh * 4 + k];
                acc = pfma(splat2(s4.x), xvp[4 * k + 0], acc);
                acc = pfma(splat2(s4.y), xvp[4 * k + 1], acc);
                acc = pfma(splat2(s4.z), xvp[4 * k + 2], acc);
                acc = pfma(splat2(s4.w), xvp[4 * k + 3], acc);
            }
            float a0 = acc.x, a1 = acc.y;
            // 4-lane butterfly: all lanes end with the full deterministic sum
            a0 += pswap(a0);  a0 += pswap2(a0);
            a1 += pswap(a1);  a1 += pswap2(a1);
            float vv = (qh & 1) ? a1 : a0;
            int   cc = c0 + (qh & 1);
            if (qh < 2) {
                if (r < DEG) ecol[cc][r + ((r >= HP) ? 3 : 0)] = __expf(vv);
                else         ssim[cc] = vv;
            }
        } else {
            if (qh < 2) ecol[c0 + (qh & 1)][r + ((r >= HP) ? 3 : 0)] = 0.0f;
        }
    }
    __syncthreads();

    // ---- gather own half of T, packed by q-pairs straight from LDS ----
    v2f T2[HP][5];                           // T2[pp][qq] = (T[pp][2qq], T[pp][2qq+1])
    float a[HP];
    v2f bv2[5];
    #pragma unroll
    for (int qq = 0; qq < 5; ++qq)
        bv2[qq] = mk2((2 * qq < dtj) ? 1.0f : 0.0f, (2 * qq + 1 < dtj) ? 1.0f : 0.0f);

    const int sbase = h << 3;                // h=0 -> slots 0..4; h=1 -> 8..12
    #pragma unroll
    for (int qq = 0; qq < 5; ++qq) {
        const float* cp0 = &ecol[ntq[2 * qq]][sbase];
        const float* cp1 = &ecol[ntq[2 * qq + 1]][sbase];
        float4 A4 = *(const float4*)cp0;     // ds_read_b128
        float  Ae = cp0[4];                  // ds_read_b32
        float4 B4 = *(const float4*)cp1;
        float  Be = cp1[4];
        T2[0][qq] = mk2(A4.x, B4.x);
        T2[1][qq] = mk2(A4.y, B4.y);
        T2[2][qq] = mk2(A4.z, B4.z);
        T2[3][qq] = mk2(A4.w, B4.w);
        T2[4][qq] = mk2(Ae,   Be);
    }
    #pragma unroll
    for (int pp = 0; pp < HP; ++pp) {
        int p = h * HP + pp;
        v2f s01 = T2[pp][0] + T2[pp][1];
        v2f s23 = T2[pp][2] + T2[pp][3];
        v2f s   = (s01 + s23) + T2[pp][4];
        float sum = s.x + s.y;
        a[pp] = (p < dsi) ? __builtin_amdgcn_rcpf(sum) * 10.0f : 0.0f;
    }

    // ---- 5 Sinkhorn iterations (packed matvecs) ----
    #pragma unroll 1
    for (int it = 0; it < NUM_STEPS; ++it) {
        // column phase: per q-pair, split 3+2 packed chains, DPP per component
        #pragma unroll
        for (int qq = 0; qq < 5; ++qq) {
            v2f cA = pfma(splat2(a[2]), T2[2][qq],
                      pfma(splat2(a[1]), T2[1][qq], T2[0][qq] * splat2(a[0])));
            v2f cB = pfma(splat2(a[4]), T2[4][qq], T2[3][qq] * splat2(a[3]));
            v2f c  = cA + cB;
            float cx = c.x + pswap(c.x);     // identical on both lanes
            float cy = c.y + pswap(c.y);
            float b0 = bv2[qq].x, b1 = bv2[qq].y;
            // masked q: b==0 -> 0 * rcp(1e-8) == 0 exactly (no predication)
            bv2[qq].x = b0 * __builtin_amdgcn_rcpf(fmaf(b0, cx, 1e-8f));
            bv2[qq].y = b1 * __builtin_amdgcn_rcpf(fmaf(b1, cy, 1e-8f));
        }
        // row phase: packed q-pair chains + horizontal add
        #pragma unroll
        for (int pp = 0; pp < HP; ++pp) {
            v2f r1 = pfma(T2[pp][1], bv2[1], T2[pp][0] * bv2[0]);
            v2f r2 = pfma(T2[pp][3], bv2[3], T2[pp][2] * bv2[2]);
            v2f rr = pfma(T2[pp][4], bv2[4], r1 + r2);
            float r = rr.x + rr.y;
            float ap = a[pp];
            // masked row: ap==0 and r==0 -> 0 * rcp(1e-8) == 0 exactly
            a[pp] = ap * __builtin_amdgcn_rcpf(fmaf(ap, r, 1e-8f));
        }
    }

    // ---- argmax per own row over T*b in exact q order; cost = ln(T[best]) ----
    float cpart = 0.f;
    #pragma unroll
    for (int pp = 0; pp < HP; ++pp) {
        int p = h * HP + pp;
        if (p < dsi) {
            float best = T2[pp][0].x * bv2[0].x;   // q=0 always valid (deg>=1)
            float bT   = T2[pp][0].x;
            #pragma unroll
            for (int qq = 0; qq < 5; ++qq) {
                float vx = T2[pp][qq].x * bv2[qq].x;
                float vy = T2[pp][qq].y * bv2[qq].y;
                if (qq > 0 && vx > best) { best = vx; bT = T2[pp][qq].x; }
                if (vy > best)           { best = vy; bT = T2[pp][qq].y; }
            }
            cpart += __logf(bT);              // == sim value (roundtrip ~5e-6)
        }
    }
    float cost = cpart + pswap(cpart);           // identical on both lanes

    float M = (float)((dsi > dtj) ? dsi : dtj);
    float simv = ssim[j];
    float v = fmaf(cost, __builtin_amdgcn_rcpf(1.0f + M), simv);

    // ---- one-barrier block softmax over j (each pair's v counted twice) ----
    float wm = v;                                // wave max: all lanes need it
    #pragma unroll
    for (int off = 32; off; off >>= 1) wm = fmaxf(wm, __shfl_xor(wm, off));
    float ew = __expf(v - wm);
    // wave sum via DPP tree (0-fill OOB); total lands on lane 63
    float ws = ew;
    ws += dpp0<0x111>(ws);                       // row_shr:1
    ws += dpp0<0x112>(ws);                       // row_shr:2
    ws += dpp0<0x114>(ws);                       // row_shr:4
    ws += dpp0<0x118>(ws);                       // row_shr:8
    ws += dpp0<0x142>(ws);                       // row_bcast15
    ws += dpp0<0x143>(ws);                       // row_bcast31
    int wsl = tid >> 6;
    if ((tid & 63) == 63) { smax[wsl] = wm; ssum[wsl] = ws; }
    __syncthreads();
    float bm = fmaxf(fmaxf(smax[0], smax[1]), fmaxf(smax[2], smax[3]));
    float bs = (ssum[0] * __expf(smax[0] - bm) + ssum[1] * __expf(smax[1] - bm) +
                ssum[2] * __expf(smax[2] - bm) + ssum[3] * __expf(smax[3] - bm)) * 0.5f;
    float e = ew * __expf(wm - bm);

    if (h == 0) out[(size_t)gs * NN + j] = e * __builtin_amdgcn_rcpf(bs);
}

// ---------------------------------------------------------------------------
extern "C" void kernel_launch(void* const* d_in, const int* in_sizes, int n_in,
                              void* d_out, int out_size, void* d_ws, size_t ws_size,
                              hipStream_t stream) {
    (void)in_sizes; (void)n_in; (void)out_size; (void)d_ws; (void)ws_size;
    const float* x_s  = (const float*)d_in[0];
    const int*   ei_s = (const int*)  d_in[1];
    const float* x_t  = (const float*)d_in[3];
    const int*   ei_t = (const int*)  d_in[4];
    float* out = (float*)d_out;

    const int* dst_s = ei_s + NB * NN * DEG;   // second row of edge_index
    const int* dst_t = ei_t + NB * NN * DEG;

    hipLaunchKernelGGL(fused_kernel, dim3(NB * NN), dim3(256), 0, stream,
                       x_s, x_t, dst_s, dst_t, out);
}

// Round 14
// 21.428 us; speedup vs baseline: 1.3814x; 1.0164x over previous
//
#include <hip/hip_runtime.h>
#include <stdint.h>
#include <math.h>

#define NB 8
#define NN 128
#define NC 64
#define DEG 10
#define HP (DEG / 2)
#define NUM_STEPS 5

typedef float v2f __attribute__((ext_vector_type(2)));

__device__ __forceinline__ v2f mk2(float x, float y) { v2f r; r.x = x; r.y = y; return r; }
__device__ __forceinline__ v2f splat2(float x)       { v2f r; r.x = x; r.y = x; return r; }
__device__ __forceinline__ v2f pfma(v2f a, v2f b, v2f c) {
    return __builtin_elementwise_fma(a, b, c);     // -> v_pk_fma_f32 on gfx950
}

// DPP lane swaps within a quad (pure VALU, no LDS pipe, convergent callers).
__device__ __forceinline__ float pswap(float x) {   // lanes 2k <-> 2k+1
    return __int_as_float(__builtin_amdgcn_update_dpp(
        0, __float_as_int(x), 0xB1, 0xF, 0xF, false));
}
__device__ __forceinline__ float pswap2(float x) {  // quad_perm [2,3,0,1]
    return __int_as_float(__builtin_amdgcn_update_dpp(
        0, __float_as_int(x), 0x4E, 0xF, 0xF, false));
}
// DPP with 0-fill out-of-bounds: safe for SUM reductions (adds 0).
template<int C>
__device__ __forceinline__ float dpp0(float x) {
    return __int_as_float(__builtin_amdgcn_update_dpp(
        0, __float_as_int(x), C, 0xF, 0xF, true));
}

// ---------------------------------------------------------------------------
// Single fused kernel. Block = (b,i), 256 threads. R13 structure with:
//  - LAST ROW PHASE REMOVED (dead code: the final row normalization scales
//    each row by a positive constant -> row-argmax invariant, exactly as in
//    the reference where argmax is over the row-normalized S; cost reads raw
//    S_hat). Loop is 4x(col+row) + 1 final col. Bit-exact same output.
//  - argmax products packed (v_pk_mul), compare order x-then-y per pair ==
//    exact q order, strict > keeps first max.
//
// SIM phase: thread (jp = tid>>2, qh = tid&3) owns a QUARTER of x_t rows
// 2jp, 2jp+1 packed as v2f xvp[16]; broadcast-reads each xsl[r] quarter,
// 16 packed FMAs per row; 2-step DPP butterfly per component; qh==0/1 write
// cols 2jp/2jp+1. exp(sim) stored TRANSPOSED: ecol[col][slot], slot(r) =
// r + (r>=5 ? 3 : 0) (16B-aligned b128 at slots 0/8). Rows p>=dsi zeroed;
// col NN all-zero -> T-gather needs no mask. Raw sim recovered as ln(T);
// self row in ssim[].
//
// SINKHORN: j = tid>>1, h = tid&1; rank-factored S[p][q] ==
// T[p][q]*a[p]*b[q], T = exp(S_hat) (exp monotone + row-softmax normalizes
// => max-subtraction unnecessary; |sim| <~ 45 keeps products finite).
// T packed by q-pairs at the gather. Thread h owns rows h*5..h*5+4; col
// sums split p-wise, combined via DPP per component; b/a updates
// unpredicated (masked lanes self-preserve: 0*rcp(1e-8)==0). argmax_q S ==
// argmax_q T*b (a>0 const/row); q=0 always valid (deg>=1), valid entries
// strictly positive -> zero slots never win. cost = ln(T[best]) via __logf
// (roundtrip ~5e-6 << bf16 granularity).
// Tail: ONE barrier — wave max via shfl butterfly, wave sum via DPP
// shr/bcast tree (lane 63 writes); block combine ssum[w]*exp(smax[w]-bm);
// each pair's v appears twice -> *0.5.
// ---------------------------------------------------------------------------
__global__ __launch_bounds__(256, 4) void fused_kernel(
    const float* __restrict__ xs, const float* __restrict__ xt,
    const int* __restrict__ dst_s, const int* __restrict__ dst_t,
    float* __restrict__ out)
{
    __shared__ float  ssim[NN];              // self sim row (for epilogue)
    __shared__ float  ecol[NN + 1][20];      // transposed exp rows; col NN zero
    __shared__ float4 xsl[DEG + 1][NC / 4];
    __shared__ float  smax[4], ssum[4];

    const int bi  = blockIdx.x;
    const int b   = bi >> 7, i = bi & 127;
    const int tid = threadIdx.x;
    const int gs  = b * NN + i;

    // ---- s-side neighbor mask (block-uniform) ----
    unsigned long long slo = 0ull, shi = 0ull;
    #pragma unroll
    for (int k = 0; k < DEG; ++k) {
        int d = dst_s[gs * DEG + k] & (NN - 1);
        if (d < 64) slo |= 1ull << d; else shi |= 1ull << (d - 64);
    }
    const int dsi = __popcll(slo) + __popcll(shi);

    // ---- sim-phase mapping: quarter-row, two columns per thread (packed) ----
    const int qh = tid & 3;                  // quarter id
    const int jp = tid >> 2;                 // column pair 0..63
    const int c0 = 2 * jp;                   // owned columns c0, c0+1
    v2f xvp[16];
    {
        const float4* xt0 = (const float4*)(xt + (size_t)(b * NN + c0)     * NC) + qh * 4;
        const float4* xt1 = (const float4*)(xt + (size_t)(b * NN + c0 + 1) * NC) + qh * 4;
        #pragma unroll
        for (int k = 0; k < 4; ++k) {
            float4 u = xt0[k], w = xt1[k];
            xvp[4 * k + 0] = mk2(u.x, w.x);
            xvp[4 * k + 1] = mk2(u.y, w.y);
            xvp[4 * k + 2] = mk2(u.z, w.z);
            xvp[4 * k + 3] = mk2(u.w, w.w);
        }
    }

    // ---- zero column of ecol (slots 0..12 cover all read slots) ----
    if (tid < 13) ecol[NN][tid] = 0.0f;

    // ---- stage x_s rows into LDS: threads 0..175, row = tid>>4, k = tid&15 ----
    if (tid < (DEG + 1) * 16) {
        int r = tid >> 4, k = tid & 15;
        int node = i;                        // r==10 -> self row
        if (r < DEG) {
            unsigned long long lo = slo, hi = shi; int sel = 0;
            #pragma unroll
            for (int q = 0; q < DEG; ++q) {  // static walk, scalar select
                int t;
                if (lo)      { t = __builtin_ctzll(lo);      lo &= lo - 1ull; }
                else if (hi) { t = 64 + __builtin_ctzll(hi); hi &= hi - 1ull; }
                else t = 0;
                if (q == r) sel = t;
            }
            node = sel;
        }
        if (r == DEG || r < dsi)
            xsl[r][k] = ((const float4*)(xs + (size_t)(b * NN + node) * NC))[k];
    }

    // ---- t-side neighbor list for sinkhorn pair j = tid>>1 (int2 loads) ----
    const int j = tid >> 1, h = tid & 1;
    const int gt = b * NN + j;
    unsigned long long tlo = 0ull, thi = 0ull;
    {
        const int2* dt2 = (const int2*)(dst_t + (size_t)gt * DEG);  // 40B rows, 8B-aligned
        int2 w0 = dt2[0], w1 = dt2[1], w2 = dt2[2], w3 = dt2[3], w4 = dt2[4];
        int dd[DEG] = { w0.x, w0.y, w1.x, w1.y, w2.x, w2.y, w3.x, w3.y, w4.x, w4.y };
        #pragma unroll
        for (int k = 0; k < DEG; ++k) {      // static-indexed reads of dd
            int dm = dd[k] & (NN - 1);
            if (dm < 64) tlo |= 1ull << dm; else thi |= 1ull << (dm - 64);
        }
    }
    const int dtj = __popcll(tlo) + __popcll(thi);
    int ntq[DEG];
    {
        unsigned long long lo = tlo, hi = thi;
        #pragma unroll
        for (int q = 0; q < DEG; ++q) {      // static-indexed writes
            int t;
            if (lo)      { t = __builtin_ctzll(lo);      lo &= lo - 1ull; }
            else if (hi) { t = 64 + __builtin_ctzll(hi); hi &= hi - 1ull; }
            else t = 0;
            ntq[q] = (q < dtj) ? t : NN;     // invalid -> zero column
        }
    }
    __syncthreads();

    // ---- sim dots: 4 xsl-quarter broadcast reads/row, 16 packed FMAs ----
    #pragma unroll
    for (int r = 0; r <= DEG; ++r) {
        if (r == DEG || r < dsi) {           // wave-uniform (dsi block-uniform)
            v2f acc = mk2(0.f, 0.f);
            #pragma unroll
            for (int k = 0; k < 4; ++k) {
                float4 s4 = xsl[r][qh * 4 + k];
                acc = pfma(splat2(s4.x), xvp[4 * k + 0], acc);
                acc = pfma(splat2(s4.y), xvp[4 * k + 1], acc);
                acc = pfma(splat2(s4.z), xvp[4 * k + 2], acc);
                acc = pfma(splat2(s4.w), xvp[4 * k + 3], acc);
            }
            float a0 = acc.x, a1 = acc.y;
            // 4-lane butterfly: all lanes end with the full deterministic sum
            a0 += pswap(a0);  a0 += pswap2(a0);
            a1 += pswap(a1);  a1 += pswap2(a1);
            float vv = (qh & 1) ? a1 : a0;
            int   cc = c0 + (qh & 1);
            if (qh < 2) {
                if (r < DEG) ecol[cc][r + ((r >= HP) ? 3 : 0)] = __expf(vv);
                else         ssim[cc] = vv;
            }
        } else {
            if (qh < 2) ecol[c0 + (qh & 1)][r + ((r >= HP) ? 3 : 0)] = 0.0f;
        }
    }
    __syncthreads();

    // ---- gather own half of T, packed by q-pairs straight from LDS ----
    v2f T2[HP][5];                           // T2[pp][qq] = (T[pp][2qq], T[pp][2qq+1])
    float a[HP];
    v2f bv2[5];
    #pragma unroll
    for (int qq = 0; qq < 5; ++qq)
        bv2[qq] = mk2((2 * qq < dtj) ? 1.0f : 0.0f, (2 * qq + 1 < dtj) ? 1.0f : 0.0f);

    const int sbase = h << 3;                // h=0 -> slots 0..4; h=1 -> 8..12
    #pragma unroll
    for (int qq = 0; qq < 5; ++qq) {
        const float* cp0 = &ecol[ntq[2 * qq]][sbase];
        const float* cp1 = &ecol[ntq[2 * qq + 1]][sbase];
        float4 A4 = *(const float4*)cp0;     // ds_read_b128
        float  Ae = cp0[4];                  // ds_read_b32
        float4 B4 = *(const float4*)cp1;
        float  Be = cp1[4];
        T2[0][qq] = mk2(A4.x, B4.x);
        T2[1][qq] = mk2(A4.y, B4.y);
        T2[2][qq] = mk2(A4.z, B4.z);
        T2[3][qq] = mk2(A4.w, B4.w);
        T2[4][qq] = mk2(Ae,   Be);
    }
    #pragma unroll
    for (int pp = 0; pp < HP; ++pp) {
        int p = h * HP + pp;
        v2f s01 = T2[pp][0] + T2[pp][1];
        v2f s23 = T2[pp][2] + T2[pp][3];
        v2f s   = (s01 + s23) + T2[pp][4];
        float sum = s.x + s.y;
        a[pp] = (p < dsi) ? __builtin_amdgcn_rcpf(sum) * 10.0f : 0.0f;
    }

    // ---- Sinkhorn: 4 x (col + row) + final col (last row phase is dead) ----
#define COL_PHASE()                                                            \
    {                                                                          \
        _Pragma("unroll")                                                      \
        for (int qq = 0; qq < 5; ++qq) {                                       \
            v2f cA = pfma(splat2(a[2]), T2[2][qq],                             \
                      pfma(splat2(a[1]), T2[1][qq], T2[0][qq] * splat2(a[0])));\
            v2f cB = pfma(splat2(a[4]), T2[4][qq], T2[3][qq] * splat2(a[3]));  \
            v2f c  = cA + cB;                                                  \
            float cx = c.x + pswap(c.x);     /* identical on both lanes */     \
            float cy = c.y + pswap(c.y);                                       \
            float b0 = bv2[qq].x, b1 = bv2[qq].y;                              \
            /* masked q: b==0 -> 0 * rcp(1e-8) == 0 exactly */                 \
            bv2[qq].x = b0 * __builtin_amdgcn_rcpf(fmaf(b0, cx, 1e-8f));       \
            bv2[qq].y = b1 * __builtin_amdgcn_rcpf(fmaf(b1, cy, 1e-8f));       \
        }                                                                      \
    }

    #pragma unroll 1
    for (int it = 0; it < NUM_STEPS - 1; ++it) {
        COL_PHASE()
        // row phase: packed q-pair chains + horizontal add
        #pragma unroll
        for (int pp = 0; pp < HP; ++pp) {
            v2f r1 = pfma(T2[pp][1], bv2[1], T2[pp][0] * bv2[0]);
            v2f r2 = pfma(T2[pp][3], bv2[3], T2[pp][2] * bv2[2]);
            v2f rr = pfma(T2[pp][4], bv2[4], r1 + r2);
            float r = rr.x + rr.y;
            float ap = a[pp];
            // masked row: ap==0 and r==0 -> 0 * rcp(1e-8) == 0 exactly
            a[pp] = ap * __builtin_amdgcn_rcpf(fmaf(ap, r, 1e-8f));
        }
    }
    COL_PHASE()                               // 5th col; 5th row phase dead
#undef COL_PHASE

    // ---- argmax per own row over T*b (packed muls, exact q order) ----
    float cpart = 0.f;
    #pragma unroll
    for (int pp = 0; pp < HP; ++pp) {
        int p = h * HP + pp;
        if (p < dsi) {
            v2f pr0 = T2[pp][0] * bv2[0];
            v2f pr1 = T2[pp][1] * bv2[1];
            v2f pr2 = T2[pp][2] * bv2[2];
            v2f pr3 = T2[pp][3] * bv2[3];
            v2f pr4 = T2[pp][4] * bv2[4];
            float best = pr0.x;               // q=0 always valid (deg>=1)
            float bT   = T2[pp][0].x;
            if (pr0.y > best) { best = pr0.y; bT = T2[pp][0].y; }
            if (pr1.x > best) { best = pr1.x; bT = T2[pp][1].x; }
            if (pr1.y > best) { best = pr1.y; bT = T2[pp][1].y; }
            if (pr2.x > best) { best = pr2.x; bT = T2[pp][2].x; }
            if (pr2.y > best) { best = pr2.y; bT = T2[pp][2].y; }
            if (pr3.x > best) { best = pr3.x; bT = T2[pp][3].x; }
            if (pr3.y > best) { best = pr3.y; bT = T2[pp][3].y; }
            if (pr4.x > best) { best = pr4.x; bT = T2[pp][4].x; }
            if (pr4.y > best) { best = pr4.y; bT = T2[pp][4].y; }
            cpart += __logf(bT);              // == sim value (roundtrip ~5e-6)
        }
    }
    float cost = cpart + pswap(cpart);           // identical on both lanes

    float M = (float)((dsi > dtj) ? dsi : dtj);
    float simv = ssim[j];
    float v = fmaf(cost, __builtin_amdgcn_rcpf(1.0f + M), simv);

    // ---- one-barrier block softmax over j (each pair's v counted twice) ----
    float wm = v;                                // wave max: all lanes need it
    #pragma unroll
    for (int off = 32; off; off >>= 1) wm = fmaxf(wm, __shfl_xor(wm, off));
    float ew = __expf(v - wm);
    // wave sum via DPP tree (0-fill OOB); total lands on lane 63
    float ws = ew;
    ws += dpp0<0x111>(ws);                       // row_shr:1
    ws += dpp0<0x112>(ws);                       // row_shr:2
    ws += dpp0<0x114>(ws);                       // row_shr:4
    ws += dpp0<0x118>(ws);                       // row_shr:8
    ws += dpp0<0x142>(ws);                       // row_bcast15
    ws += dpp0<0x143>(ws);                       // row_bcast31
    int wsl = tid >> 6;
    if ((tid & 63) == 63) { smax[wsl] = wm; ssum[wsl] = ws; }
    __syncthreads();
    float bm = fmaxf(fmaxf(smax[0], smax[1]), fmaxf(smax[2], smax[3]));
    float bs = (ssum[0] * __expf(smax[0] - bm) + ssum[1] * __expf(smax[1] - bm) +
                ssum[2] * __expf(smax[2] - bm) + ssum[3] * __expf(smax[3] - bm)) * 0.5f;
    float e = ew * __expf(wm - bm);

    if (h == 0) out[(size_t)gs * NN + j] = e * __builtin_amdgcn_rcpf(bs);
}

// ---------------------------------------------------------------------------
extern "C" void kernel_launch(void* const* d_in, const int* in_sizes, int n_in,
                              void* d_out, int out_size, void* d_ws, size_t ws_size,
                              hipStream_t stream) {
    (void)in_sizes; (void)n_in; (void)out_size; (void)d_ws; (void)ws_size;
    const float* x_s  = (const float*)d_in[0];
    const int*   ei_s = (const int*)  d_in[1];
    const float* x_t  = (const float*)d_in[3];
    const int*   ei_t = (const int*)  d_in[4];
    float* out = (float*)d_out;

    const int* dst_s = ei_s + NB * NN * DEG;   // second row of edge_index
    const int* dst_t = ei_t + NB * NN * DEG;

    hipLaunchKernelGGL(fused_kernel, dim3(NB * NN), dim3(256), 0, stream,
                       x_s, x_t, dst_s, dst_t, out);
}